// Round 18
// baseline (527.556 us; speedup 1.0000x reference)
//
#include <hip/hip_runtime.h>
#include <math.h>

#define B8 8
typedef unsigned short ushort_t;
typedef __attribute__((ext_vector_type(8))) short bf16x8;
typedef __attribute__((ext_vector_type(4))) float f32x4;

static __device__ __forceinline__ float sigmoidf_(float x){ return 1.f/(1.f+expf(-x)); }

static __device__ __forceinline__ ushort_t f2bf(float f){
  unsigned u = __float_as_uint(f);
  u = u + 0x7fffu + ((u>>16)&1u);
  return (ushort_t)(u>>16);
}
static __device__ __forceinline__ float bflo(unsigned q){ return __uint_as_float(q << 16); }
static __device__ __forceinline__ float bfhi(unsigned q){ return __uint_as_float(q & 0xffff0000u); }

__device__ __forceinline__ void gload_lds16(const ushort_t* g, ushort_t* l){
  __builtin_amdgcn_global_load_lds((const __attribute__((address_space(1))) unsigned int*)(const void*)g,
                                   (__attribute__((address_space(3))) unsigned int*)(void*)l, 16, 0, 0);
}

// ---------------- fused gray+laplacian+window-variance flags ----------------
__global__ __launch_bounds__(256) void k_flags2(const float* __restrict__ rgb,
                                                float* __restrict__ flags){
  __shared__ float sg[70][71];
  int bx = blockIdx.x & 7, by = (blockIdx.x >> 3) & 7, b = blockIdx.x >> 6;
  int wy0 = by*16, wx0 = bx*16;
  int y0 = 4*wy0 - 1, x0 = 4*wx0 - 1;
  const float* p = rgb + (size_t)b*3*262144;
  int tid = threadIdx.x;
  for (int i = tid; i < 70*70; i += 256){
    int r = i/70, cX = i%70;
    int y = y0 + r, x = x0 + cX;
    float v = 0.f;
    if (y>=0 && y<512 && x>=0 && x<512){
      int ii = y*512+x;
      v = 0.299f*p[ii] + 0.587f*p[ii+262144] + 0.114f*p[ii+524288];
      v = fminf(fmaxf(v*255.f, 0.f), 255.f);
    }
    sg[r][cX] = v;
  }
  __syncthreads();
  int wy = wy0 + (tid>>4), wx = wx0 + (tid&15);
  if (wy > 126 || wx > 126) return;
  int ry = 4*(tid>>4) + 1, rx = 4*(tid&15) + 1;
  float s1 = 0.f, s2 = 0.f;
  #pragma unroll
  for (int iy=0; iy<8; ++iy){
    int r = ry+iy;
    #pragma unroll
    for (int ix=0; ix<8; ++ix){
      int cX = rx+ix;
      float c = sg[r][cX];
      float lap = sg[r-1][cX] + sg[r+1][cX] + sg[r][cX-1] + sg[r][cX+1] - 4.f*c;
      s1 += lap; s2 += lap*lap;
    }
  }
  float var = (s2 - s1*s1*(1.f/64.f)) * (1.f/63.f);
  flags[(size_t)b*16129 + wy*127 + wx] = (var < 50.f) ? 1.f : 0.f;
}

// ---------------- all three downsampled mask pairs in one launch ----------------
__global__ void k_masks3(const float* __restrict__ flags, const float* __restrict__ depth,
                         float* __restrict__ ri0, float* __restrict__ di0,
                         float* __restrict__ ri1, float* __restrict__ di1,
                         float* __restrict__ ri2, float* __restrict__ di2){
  int idx = blockIdx.x*256 + threadIdx.x;
  const int n0 = 8*4096, n1 = 8*1024, n2 = 8*256;
  float* ri; float* di; int h, st, i2;
  if (idx < n0){ ri=ri0; di=di0; h=64; st=8;  i2=idx; }
  else if (idx < n0+n1){ ri=ri1; di=di1; h=32; st=16; i2=idx-n0; }
  else if (idx < n0+n1+n2){ ri=ri2; di=di2; h=16; st=32; i2=idx-n0-n1; }
  else return;
  int b = i2/(h*h), i = i2%(h*h);
  int y = (i/h)*st, x = (i%h)*st;
  const float* f = flags + (size_t)b*16129;
  int fy = y>>2, fx = x>>2;
  float v = f[fy*127+fx];
  if (y>0)         v = fmaxf(v, f[(fy-1)*127+fx]);
  if (x>0)         v = fmaxf(v, f[fy*127+fx-1]);
  if (y>0 && x>0)  v = fmaxf(v, f[(fy-1)*127+fx-1]);
  ri[i2] = v;
  const int IHW = 262144;
  di[i2] = (depth[(size_t)b*3*IHW + 2*IHW + (size_t)y*512 + x] <= 0.f) ? 1.f : 0.f;
}

// ---------------- weights -> bf16, K-order (cb outer, kq inner): k' = (cb*9+kq)*64+cin ------
template<int C>
__global__ __launch_bounds__(256) void k_wrd2(const float* __restrict__ w, ushort_t* __restrict__ outp){
  __shared__ float swp[9*C];
  int co = blockIdx.x, tid = threadIdx.x;
  const int n = 9*C;
  const float* src = w + (size_t)co*n;
  for (int i=tid;i<n;i+=256) swp[i]=src[i];
  __syncthreads();
  ushort_t* dst = outp + (size_t)co*n;
  for (int j=tid;j<n;j+=256){
    int cb  = j / 576;
    int rem = j - cb*576;
    int kq  = rem >> 6;
    int cin = rem & 63;
    dst[j] = f2bf(swp[(cb*64 + cin)*9 + kq]);
  }
}

// ---------------- FUSED: feat -> padded NHWC bf16 + channel-row sums + per-position stats ----
template<int C, int H, int W>
__global__ __launch_bounds__(256) void k_prep(const float* __restrict__ rgbf,
                                              const float* __restrict__ depf,
                                              ushort_t* __restrict__ outp,
                                              float* __restrict__ gpart,
                                              float* __restrict__ pmean,
                                              float* __restrict__ pmax_){
  const int W2 = W+2, H2 = H+2, CB = C/64;
  const int NHSZ = B8*H2*W2*C;
  const int HW = H*W;
  __shared__ float st[64*66];
  __shared__ float red[4][64];
  int bi = blockIdx.x;
  int f  = bi & 1; bi >>= 1;          // 0=rgb feat, 1=dep feat
  int cb = bi % CB; bi /= CB;
  int yy = bi % H2;
  int b  = bi / H2;
  int tid = threadIdx.x;
  const float* in = (f==0) ? rgbf : depf;
  int ndir = f ^ 1;                    // nhwc dest dir
  ushort_t* outrow = outp + (size_t)ndir*NHSZ + ((size_t)(b*H2 + yy)*W2)*C + cb*64;
  bool pad_row = (yy == 0) || (yy == H2-1);
  if (!pad_row){
    int y = yy-1;
    const float* src = in + ((size_t)(b*C + cb*64)*H + y)*W;
    for (int i=tid; i<64*W; i+=256){
      int c = i / W, x = i % W;
      st[x*66 + c] = src[(size_t)c*H*W + x];
    }
  }
  __syncthreads();
  // (a) nhwc write
  for (int j=tid; j<W2*8; j+=256){
    int x = j >> 3, cc = (j & 7)*8;
    ushort_t tmp[8];
    if (pad_row || x == 0 || x == W2-1){
      #pragma unroll
      for (int q=0;q<8;++q) tmp[q]=0;
    } else {
      const float* sp = &st[(x-1)*66 + cc];
      float2 a0 = *(const float2*)(sp+0);
      float2 a1 = *(const float2*)(sp+2);
      float2 a2 = *(const float2*)(sp+4);
      float2 a3 = *(const float2*)(sp+6);
      tmp[0]=f2bf(a0.x); tmp[1]=f2bf(a0.y); tmp[2]=f2bf(a1.x); tmp[3]=f2bf(a1.y);
      tmp[4]=f2bf(a2.x); tmp[5]=f2bf(a2.y); tmp[6]=f2bf(a3.x); tmp[7]=f2bf(a3.y);
    }
    *(bf16x8*)&outrow[(size_t)x*C + cc] = *(bf16x8*)tmp;
  }
  if (pad_row) return;
  int y = yy - 1;
  // (b) per-channel row sums (4 threads/channel, LDS reduce)
  {
    int c = tid & 63, quarter = tid >> 6;
    float s = 0.f;
    for (int x = quarter; x < W; x += 4) s += st[x*66 + c];
    red[quarter][c] = s;
  }
  // (c) per-position sum/max over 64 channels (4-lane slices)
  if (tid < W*4){
    int x = tid >> 2, sl = tid & 3;
    float ps = 0.f, pmx = -INFINITY;
    #pragma unroll
    for (int k=0;k<16;++k){
      float v = st[x*66 + sl*16 + k];
      ps += v; pmx = fmaxf(pmx, v);
    }
    ps += __shfl_xor(ps, 1); pmx = fmaxf(pmx, __shfl_xor(pmx, 1));
    ps += __shfl_xor(ps, 2); pmx = fmaxf(pmx, __shfl_xor(pmx, 2));
    if (sl == 0){
      size_t po = ((size_t)f*CB + cb)*((size_t)B8*HW) + (size_t)b*HW + (size_t)y*W + x;
      pmean[po] = ps; pmax_[po] = pmx;
    }
  }
  __syncthreads();
  if (tid < 64){
    float t4 = red[0][tid]+red[1][tid]+red[2][tid]+red[3][tid];
    gpart[(((size_t)f*B8 + b)*H + y)*C + (size_t)cb*64 + tid] = t4;
  }
}

// ---------------- implicit-GEMM conv: 128x128 tile, 4 waves, 2 blocks/CU, pipelined --------
// Same pipelined 2-barrier schedule as the proven 256^2 kernel, mechanically halved so two
// independent blocks co-reside per CU (64KB LDS) and hide each other's barrier stalls.
//   P0: read B+Aq0+Aq1, stage A-h1(t+1), MFMA q0, lgkm(0), BARRIER-1
//   P1: read Aq2, stage B-h0(t+2), MFMA q1
//   P2: read Aq3, stage B-h1(t+2), MFMA q2
//   P3: stage A-h0(t+2), MFMA q3, vmcnt(6), BARRIER-2
template<int C, int H, int W, int KS>
__global__ __launch_bounds__(256, 2)
void k_gemm_conv(const ushort_t* __restrict__ Aw, const ushort_t* __restrict__ nh,
                 ushort_t* __restrict__ Gm){
  const int K9 = 9*C;
  const int HW = H*W;
  const int N  = B8*HW;
  const int H2 = H+2, W2 = W+2;
  const int NT_N = N/128, NT_M = C/128;
  const int KCT = 36;
  const int NHSZ = B8*H2*W2*C;
  __shared__ ushort_t sA[2][8192];        // [slot][quad-major 128 rows][64]
  __shared__ ushort_t sB[2][8192];        // [slot][128 rows][64]
  int tid = threadIdx.x;

  const int nwg = 2*KS*NT_M*NT_N;         // = 1024 for all scales
  const int MK  = 2*KS*NT_M;
  int bid = blockIdx.x;
  int swz = (bid & 7)*(nwg >> 3) + (bid >> 3);
  int mk  = swz % MK;
  int n_t = swz / MK;
  int m_t = mk % NT_M;
  int kz2 = mk / NT_M;
  int dir = kz2 / KS, kz = kz2 % KS;

  const ushort_t* nhd = nh + (size_t)dir*NHSZ;
  int m0 = m_t*128, n0 = n_t*128;
  int l = tid & 63, wv_id = tid >> 6;
  int wm = wv_id >> 1, wn = wv_id & 1;    // 2M x 2N waves
  int lrow = l & 15, lq = l >> 4;
  int lx7 = lrow & 7;

  // per-thread staging source bases (per half: 512 chunks, c = j*256+tid)
  long long aoffA[2][2], boffB[2][2];
  #pragma unroll
  for (int h=0; h<2; ++h){
    #pragma unroll
    for (int j=0; j<2; ++j){
      int c = j*256 + tid;
      int lr = h*64 + (c>>3);
      int slot = c & 7;
      int lslot = slot ^ (lr & 7);        // T2: pre-swizzled source
      // A quad-major: lds_row = q*32 + wm*16 + loc  (q=quad, 16 rows per wave-slice)
      int q_ = lr >> 5, wm_ = (lr>>4)&1, loc = lr & 15;
      int r = wm_*64 + q_*16 + loc;       // invert quad-major map
      aoffA[h][j] = (long long)(m0 + r)*K9 + lslot*8;
      int nn = n0 + lr;
      int b_ = nn / HW, rhw = nn % HW;
      int y = rhw / W, x = rhw % W;
      boffB[h][j] = ((long long)(b_*H2 + y + 1)*W2 + (x + 1))*(long long)C + lslot*8;
    }
  }

#define STAGE_A(s_, h_, kc_) do{                                    \
    long long oK = (long long)(kc_) << 6;                           \
    ushort_t* d0 = &sA[s_][(h_)*4096 + tid*8];                      \
    gload_lds16(Aw + aoffA[h_][0] + oK, d0);                        \
    gload_lds16(Aw + aoffA[h_][1] + oK, d0 + 2048);                 \
  }while(0)
#define STAGE_B(s_, h_, kc_) do{                                    \
    int cb_ = (kc_)/9, kq_ = (kc_) - cb_*9;                         \
    long long dv = (long long)((kq_/3 - 1)*W2 + (kq_%3 - 1))*C + ((long long)cb_<<6); \
    ushort_t* d0 = &sB[s_][(h_)*4096 + tid*8];                      \
    gload_lds16(nhd + boffB[h_][0] + dv, d0);                       \
    gload_lds16(nhd + boffB[h_][1] + dv, d0 + 2048);                \
  }while(0)

  f32x4 acc[4][4];
  #pragma unroll
  for (int i=0;i<4;++i)
    #pragma unroll
    for (int j=0;j<4;++j) acc[i][j] = (f32x4){0.f,0.f,0.f,0.f};

  int kc0 = kz*KCT;

  // prologue: tile0 fully + tile1's B halves and A-h0 (7 half-tiles, 14 loads)
  STAGE_A(0,0,kc0);   STAGE_A(0,1,kc0);
  STAGE_B(0,0,kc0);   STAGE_B(0,1,kc0);
  STAGE_B(1,0,kc0+1); STAGE_B(1,1,kc0+1);
  STAGE_A(1,0,kc0+1);
  asm volatile("s_waitcnt vmcnt(6)" ::: "memory");   // tile0's 8 loads landed
  __builtin_amdgcn_s_barrier();

  for (int t=0; t<KCT; ++t){
    int cur = t & 1, nxt = cur ^ 1;
    int kc = kc0 + t;
    bf16x8 bf[4][2], afA[2], afB[2];

    // ---- P0: read B(all) + Aq0 + Aq1(prefetch); stage A-h1(t+1); MFMA q0 ----
    #pragma unroll
    for (int ni=0;ni<4;++ni)
      #pragma unroll
      for (int kk=0;kk<2;++kk)
        bf[ni][kk] = *(const bf16x8*)&sB[cur][(wn*64 + ni*16 + lrow)*64 + ((kk*4+lq)^lx7)*8];
    #pragma unroll
    for (int kk=0;kk<2;++kk)
      afA[kk] = *(const bf16x8*)&sA[cur][(wm*16 + lrow)*64 + ((kk*4+lq)^lx7)*8];
    #pragma unroll
    for (int kk=0;kk<2;++kk)
      afB[kk] = *(const bf16x8*)&sA[cur][(32 + wm*16 + lrow)*64 + ((kk*4+lq)^lx7)*8];
    if (t+1 < KCT) STAGE_A(nxt,1,kc+1);
    __builtin_amdgcn_s_setprio(1);
    #pragma unroll
    for (int kk=0;kk<2;++kk)
      #pragma unroll
      for (int ni=0;ni<4;++ni)
        acc[0][ni] = __builtin_amdgcn_mfma_f32_16x16x32_bf16(afA[kk], bf[ni][kk], acc[0][ni], 0,0,0);
    __builtin_amdgcn_s_setprio(0);
    asm volatile("s_waitcnt lgkmcnt(0)" ::: "memory");  // drain Aq1 before barrier
    __builtin_amdgcn_sched_barrier(0);
    __builtin_amdgcn_s_barrier();                       // BARRIER-1

    // ---- P1: read Aq2; stage B-h0(t+2); MFMA q1 (regs ready, no wait) ----
    #pragma unroll
    for (int kk=0;kk<2;++kk)
      afA[kk] = *(const bf16x8*)&sA[cur][(64 + wm*16 + lrow)*64 + ((kk*4+lq)^lx7)*8];
    if (t+2 < KCT) STAGE_B(cur,0,kc+2);
    __builtin_amdgcn_s_setprio(1);
    #pragma unroll
    for (int kk=0;kk<2;++kk)
      #pragma unroll
      for (int ni=0;ni<4;++ni)
        acc[1][ni] = __builtin_amdgcn_mfma_f32_16x16x32_bf16(afB[kk], bf[ni][kk], acc[1][ni], 0,0,0);
    __builtin_amdgcn_s_setprio(0);

    // ---- P2: read Aq3; stage B-h1(t+2); MFMA q2 ----
    #pragma unroll
    for (int kk=0;kk<2;++kk)
      afB[kk] = *(const bf16x8*)&sA[cur][(96 + wm*16 + lrow)*64 + ((kk*4+lq)^lx7)*8];
    if (t+2 < KCT) STAGE_B(cur,1,kc+2);
    __builtin_amdgcn_s_setprio(1);
    #pragma unroll
    for (int kk=0;kk<2;++kk)
      #pragma unroll
      for (int ni=0;ni<4;++ni)
        acc[2][ni] = __builtin_amdgcn_mfma_f32_16x16x32_bf16(afA[kk], bf[ni][kk], acc[2][ni], 0,0,0);
    __builtin_amdgcn_s_setprio(0);

    // ---- P3: stage A-h0(t+2); MFMA q3; counted vmcnt; BARRIER-2 ----
    if (t+2 < KCT) STAGE_A(cur,0,kc+2);
    __builtin_amdgcn_s_setprio(1);
    #pragma unroll
    for (int kk=0;kk<2;++kk)
      #pragma unroll
      for (int ni=0;ni<4;++ni)
        acc[3][ni] = __builtin_amdgcn_mfma_f32_16x16x32_bf16(afB[kk], bf[ni][kk], acc[3][ni], 0,0,0);
    __builtin_amdgcn_s_setprio(0);
    if (t+2 < KCT) { asm volatile("s_waitcnt vmcnt(6)" ::: "memory"); }
    else           { asm volatile("s_waitcnt vmcnt(0)" ::: "memory"); }
    __builtin_amdgcn_sched_barrier(0);
    __builtin_amdgcn_s_barrier();                       // BARRIER-2
  }
#undef STAGE_A
#undef STAGE_B

  // ---- epilogue: C-write (bf16) ----
  ushort_t* po = Gm + (size_t)kz2*C*N;
  #pragma unroll
  for (int q=0;q<4;++q)
    #pragma unroll
    for (int ni=0;ni<4;++ni)
      #pragma unroll
      for (int r=0;r<4;++r)
        po[(size_t)(m0 + wm*64 + q*16 + lq*4 + r)*N + n0 + wn*64 + ni*16 + lrow] = f2bf(acc[q][ni][r]);
}

// ---------------- FUSED attention tail: spatial attention (sp recompute in LDS) + MLP --------
template<int C, int H, int R>
__global__ __launch_bounds__(256) void k_att(const float* __restrict__ pmean,
                                             const float* __restrict__ pmax_,
                                             const float* __restrict__ gpart,
                                             const float* __restrict__ sa,
                                             const float* __restrict__ w1,
                                             const float* __restrict__ w2,
                                             float* __restrict__ sw,
                                             float* __restrict__ cw,
                                             int Rr, float invHW){
  const int CG = C/64;
  const int HW = H*H;
  const int swB = B8*(H/R);
  __shared__ float s_sa[196];
  __shared__ float spm[(R+6)*H];
  __shared__ float spx[(R+6)*H];
  __shared__ float sg[1024];
  __shared__ float sh[64];
  int dir = blockIdx.y;
  int bx = blockIdx.x;
  int tid = threadIdx.x;
  float invC = 1.f/(float)C;

  if (bx < swB){
    if (tid < 196) s_sa[tid] = sa[tid];
    int b = bx / (H/R), rb = bx % (H/R);
    int y0 = rb*R;
    for (int i = tid; i < (R+6)*H; i += 256){
      int y = y0 - 3 + i/H;
      int x = i % H;
      float s = 0.f, m = -INFINITY;
      if (y >= 0 && y < H){
        #pragma unroll
        for (int g=0; g<CG; ++g){
          size_t po = ((size_t)dir*CG + g)*((size_t)B8*HW) + (size_t)b*HW + (size_t)y*H + x;
          s += pmean[po];
          m = fmaxf(m, pmax_[po]);
        }
      }
      spm[i] = s*invC;
      spx[i] = m;
    }
    __syncthreads();
    int x = tid % H, yl = tid / H;
    int y = y0 + yl;
    float inv_w = 2.f/(float)(H-1);
    float acc = 0.f;
    for (int ky=0;ky<7;++ky){
      int gy = y+ky-3;
      if (gy<0 || gy>=H) continue;
      float ysv = -1.f + gy*inv_w;
      int lr = yl + ky;
      for (int kx=0;kx<7;++kx){
        int gx = x+kx-3;
        if (gx<0 || gx>=H) continue;
        float xsv = -1.f + gx*inv_w;
        int kk = ky*7+kx;
        acc += s_sa[kk]*spm[lr*H+gx] + s_sa[49+kk]*spx[lr*H+gx]
             + s_sa[98+kk]*xsv + s_sa[147+kk]*ysv;
      }
    }
    sw[(size_t)dir*B8*HW + (size_t)b*HW + (size_t)y*H + x] = sigmoidf_(acc);
  } else {
    int b = bx - swB;
    int Rch = C/16;
    const float* gp = gpart + (((size_t)dir*B8 + b)*H)*C;
    for (int c=tid;c<C;c+=256){
      float s = 0.f;
      for (int sp=0; sp<H; ++sp) s += gp[(size_t)sp*C + c];
      sg[c] = s*invHW;
    }
    __syncthreads();
    int r = tid>>2, q = tid&3;
    if (r < Rch){
      float s = 0.f;
      for (int c=q;c<C;c+=4) s += w1[(size_t)r*C + c]*sg[c];
      s += __shfl_xor(s,1); s += __shfl_xor(s,2);
      if (q==0) sh[r] = fmaxf(s, 0.f);
    }
    __syncthreads();
    for (int c2=tid; c2<C; c2+=256){
      float s = 0.f;
      for (int rr=0;rr<Rch;++rr) s += w2[(size_t)c2*Rch + rr]*sh[rr];
      cw[(size_t)dir*B8*C + (size_t)b*C + c2] = sigmoidf_(s);
    }
  }
}

// ---------------- fused BN stats + masked compose; G row cached in dynamic LDS --------------
__global__ __launch_bounds__(256)
void k_bnfinal(const float* __restrict__ rgbf, const float* __restrict__ depf,
               const ushort_t* __restrict__ G,
               const float* __restrict__ g, const float* __restrict__ bb,
               const float* __restrict__ swp, const float* __restrict__ cwp,
               const float* __restrict__ ri, const float* __restrict__ di,
               float* __restrict__ out_r, float* __restrict__ out_d,
               int C, int HW, int hwShift, int ks){
  extern __shared__ char bnf_smem[];
  int c = blockIdx.x, dir = blockIdx.y, tid = threadIdx.x;
  int N = B8*HW;
  size_t MN = (size_t)C*N;
  const ushort_t* p0 = G + (size_t)dir*ks*MN + (size_t)c*N;
  const float* main_ = (dir==0) ? rgbf : depf;
  const float* mask  = (dir==0) ? ri : di;
  float* out = (dir==0) ? out_r : out_d;

  float s1 = 0.f, s2 = 0.f;
  if (ks == 1){
    uint4* cache = (uint4*)bnf_smem;
    for (int i = tid*8; i < N; i += 2048){
      uint4 q = *(const uint4*)(p0 + i);
      cache[i>>3] = q;
      float v0=bflo(q.x), v1=bfhi(q.x), v2=bflo(q.y), v3=bfhi(q.y);
      float v4=bflo(q.z), v5=bfhi(q.z), v6=bflo(q.w), v7=bfhi(q.w);
      s1 += v0+v1+v2+v3+v4+v5+v6+v7;
      s2 += v0*v0+v1*v1+v2*v2+v3*v3+v4*v4+v5*v5+v6*v6+v7*v7;
    }
  } else {
    float* cache = (float*)bnf_smem;
    for (int i = tid*8; i < N; i += 2048){
      float v[8];
      #pragma unroll
      for (int q=0;q<8;++q) v[q]=0.f;
      for (int kz=0; kz<ks; ++kz){
        uint4 q = *(const uint4*)(p0 + (size_t)kz*MN + i);
        v[0]+=bflo(q.x); v[1]+=bfhi(q.x); v[2]+=bflo(q.y); v[3]+=bfhi(q.y);
        v[4]+=bflo(q.z); v[5]+=bfhi(q.z); v[6]+=bflo(q.w); v[7]+=bfhi(q.w);
      }
      #pragma unroll
      for (int q=0;q<8;++q){ cache[i+q] = v[q]; s1 += v[q]; s2 += v[q]*v[q]; }
    }
  }
  __shared__ float sb1[4], sb2[4];
  __shared__ float sab[2];
  #pragma unroll
  for (int off=32; off; off>>=1){ s1 += __shfl_down(s1,off); s2 += __shfl_down(s2,off); }
  int wid = tid>>6;
  if ((tid&63)==0){ sb1[wid]=s1; sb2[wid]=s2; }
  __syncthreads();
  if (tid==0){
    float t1 = sb1[0]+sb1[1]+sb1[2]+sb1[3];
    float t2 = sb2[0]+sb2[1]+sb2[2]+sb2[3];
    float Nf = (float)N;
    float mean = t1/Nf;
    float var  = t2/Nf - mean*mean;
    float a = g[c] / sqrtf(var + 1e-5f);
    sab[0] = a;
    sab[1] = bb[c] - mean*a;
  }
  __syncthreads();
  float a = sab[0], bta = sab[1];

  for (int i = tid*8; i < N; i += 2048){
    float v[8];
    if (ks == 1){
      uint4 q = ((const uint4*)bnf_smem)[i>>3];
      v[0]=bflo(q.x); v[1]=bfhi(q.x); v[2]=bflo(q.y); v[3]=bfhi(q.y);
      v[4]=bflo(q.z); v[5]=bfhi(q.z); v[6]=bflo(q.w); v[7]=bfhi(q.w);
    } else {
      #pragma unroll
      for (int q=0;q<8;++q) v[q] = ((const float*)bnf_smem)[i+q];
    }
    int b  = i >> hwShift;
    int hw = i - (b << hwShift);
    const float* mkp = mask + (size_t)b*HW + hw;
    const float* mnp = main_ + ((size_t)b*C + c)*HW + hw;
    const float* swq = swp + (size_t)dir*B8*HW + (size_t)b*HW + hw;
    float cwv = 2.f * cwp[(size_t)dir*B8*C + (size_t)b*C + c];
    float4 mk0 = *(const float4*)(mkp),   mk1 = *(const float4*)(mkp+4);
    float4 mn0 = *(const float4*)(mnp),   mn1 = *(const float4*)(mnp+4);
    float4 sw0 = *(const float4*)(swq),   sw1 = *(const float4*)(swq+4);
    float4 o0, o1;
    o0.x = (mk0.x > 0.5f) ? fmaxf(a*v[0] + bta, 0.f)*sw0.x*cwv : mn0.x;
    o0.y = (mk0.y > 0.5f) ? fmaxf(a*v[1] + bta, 0.f)*sw0.y*cwv : mn0.y;
    o0.z = (mk0.z > 0.5f) ? fmaxf(a*v[2] + bta, 0.f)*sw0.z*cwv : mn0.z;
    o0.w = (mk0.w > 0.5f) ? fmaxf(a*v[3] + bta, 0.f)*sw0.w*cwv : mn0.w;
    o1.x = (mk1.x > 0.5f) ? fmaxf(a*v[4] + bta, 0.f)*sw1.x*cwv : mn1.x;
    o1.y = (mk1.y > 0.5f) ? fmaxf(a*v[5] + bta, 0.f)*sw1.y*cwv : mn1.y;
    o1.z = (mk1.z > 0.5f) ? fmaxf(a*v[6] + bta, 0.f)*sw1.z*cwv : mn1.z;
    o1.w = (mk1.w > 0.5f) ? fmaxf(a*v[7] + bta, 0.f)*sw1.w*cwv : mn1.w;
    float* op = out + ((size_t)b*C + c)*HW + hw;
    *(float4*)(op)   = o0;
    *(float4*)(op+4) = o1;
  }
}

extern "C" void kernel_launch(void* const* d_in, const int* in_sizes, int n_in,
                              void* d_out, int out_size, void* d_ws, size_t ws_size,
                              hipStream_t stream){
  (void)in_sizes; (void)n_in; (void)out_size; (void)ws_size;
  const int B = B8;
  const float* rgb_feat[3] = {(const float*)d_in[0], (const float*)d_in[2], (const float*)d_in[4]};
  const float* dep_feat[3] = {(const float*)d_in[1], (const float*)d_in[3], (const float*)d_in[5]};
  const float* rgb_img = (const float*)d_in[6];
  const float* dep_img = (const float*)d_in[7];

  const int Cs[3]   = {256, 512, 1024};
  const int hs[3]   = {64, 32, 16};
  const int HWs[3]  = {64*64, 32*32, 16*16};
  const int KSs[3]  = {1, 2, 4};
  const int HWSH[3] = {12, 10, 8};
  const unsigned BNSM[3] = {65536, 32768, 8192};   // bnfinal dynamic LDS bytes

  float* ws = (float*)d_ws;
  ushort_t* Gm = (ushort_t*)ws;            // 16,777,216 bf16 (= 8,388,608 floats)
  float* flags = ws;                       // dead before gemm writes Gm
  float* rdbase = ws + 8388608;
  float* ri[3]; float* di[3];
  {
    size_t o = 0;
    for (int s=0;s<3;++s){
      ri[s] = rdbase + o; o += (size_t)B*hs[s]*hs[s];
      di[s] = rdbase + o; o += (size_t)B*hs[s]*hs[s];
    }
  }
  float* SB = rdbase + 86016;              // scratch base (nhbf | wbf)
  float* ST = SB + 9220096;                // stats (written by k_prep alongside nhbf)
  float* swb    = ST + 0;         // 65536
  float* gpart  = ST + 65536;     // 262144  [dir][b][H][C]
  float* cwb    = ST + 327680;    // 16384
  float* pmeanp = ST + 344064;    // 262144  [dir][CG][B*HW]
  float* pmaxp  = ST + 606208;    // 262144  -> ends 868,352

  // stage A: masks
  k_flags2<<<512, 256, 0, stream>>>(rgb_img, flags);
  k_masks3<<<168, 256, 0, stream>>>(flags, dep_img, ri[0], di[0], ri[1], di[1], ri[2], di[2]);

  const size_t outoff_r[3] = {0,         8388608u,  12582912u};
  const size_t outoff_d[3] = {14680064u, 23068672u, 27262976u};
  float* outp = (float*)d_out;

  for (int s=0;s<3;++s){
    const float* ftw = (const float*)d_in[8 +6*s];
    const float* bng = (const float*)d_in[9 +6*s];
    const float* bnb = (const float*)d_in[10+6*s];
    const float* saw = (const float*)d_in[11+6*s];
    const float* ca1 = (const float*)d_in[12+6*s];
    const float* ca2 = (const float*)d_in[13+6*s];
    int C = Cs[s], HW = HWs[s], h = hs[s];
    int BHW = B*HW;
    int ks = KSs[s];

    size_t nh_f = (size_t)B*(h+2)*(h+2)*C;           // shorts per dir; 2 dirs = nh_f floats
    ushort_t* nhbf = (ushort_t*)SB;
    ushort_t* wbf  = (ushort_t*)(SB + nh_f);

    if (s==0) k_wrd2<256> <<<256,  256, 0, stream>>>(ftw, wbf);
    if (s==1) k_wrd2<512> <<<512,  256, 0, stream>>>(ftw, wbf);
    if (s==2) k_wrd2<1024><<<1024, 256, 0, stream>>>(ftw, wbf);

    {
      unsigned nb = (unsigned)(B*(h+2)*(C/64)*2);
      if (s==0) k_prep<256, 64,64><<<nb, 256, 0, stream>>>(rgb_feat[s], dep_feat[s], nhbf, gpart, pmeanp, pmaxp);
      if (s==1) k_prep<512, 32,32><<<nb, 256, 0, stream>>>(rgb_feat[s], dep_feat[s], nhbf, gpart, pmeanp, pmaxp);
      if (s==2) k_prep<1024,16,16><<<nb, 256, 0, stream>>>(rgb_feat[s], dep_feat[s], nhbf, gpart, pmeanp, pmaxp);
    }

    if (s==0) k_gemm_conv<256, 64,64,1><<<1024, 256, 0, stream>>>(wbf, nhbf, Gm);
    if (s==1) k_gemm_conv<512, 32,32,2><<<1024, 256, 0, stream>>>(wbf, nhbf, Gm);
    if (s==2) k_gemm_conv<1024,16,16,4><<<1024, 256, 0, stream>>>(wbf, nhbf, Gm);

    // fused attention tail (spatial attn + channel MLP in one launch)
    {
      float invHW = 1.f/(float)HW;
      if (s==0) k_att<256, 64, 4><<<dim3((unsigned)(B*16 + B),2), 256, 0, stream>>>(pmeanp, pmaxp, gpart, saw, ca1, ca2, swb, cwb, 0, invHW);
      if (s==1) k_att<512, 32, 8><<<dim3((unsigned)(B*4  + B),2), 256, 0, stream>>>(pmeanp, pmaxp, gpart, saw, ca1, ca2, swb, cwb, 0, invHW);
      if (s==2) k_att<1024,16,16><<<dim3((unsigned)(B*1  + B),2), 256, 0, stream>>>(pmeanp, pmaxp, gpart, saw, ca1, ca2, swb, cwb, 0, invHW);
    }

    k_bnfinal<<<dim3(C,2), 256, BNSM[s], stream>>>(
        rgb_feat[s], dep_feat[s], Gm, bng, bnb, swb, cwb,
        ri[s], di[s], outp + outoff_r[s], outp + outoff_d[s], C, HW, HWSH[s], ks);
  }
}

// Round 19
// 454.239 us; speedup vs baseline: 1.1614x; 1.1614x over previous
//
#include <hip/hip_runtime.h>
#include <math.h>

#define B8 8
typedef unsigned short ushort_t;
typedef __attribute__((ext_vector_type(8))) short bf16x8;
typedef __attribute__((ext_vector_type(4))) float f32x4;

static __device__ __forceinline__ float sigmoidf_(float x){ return 1.f/(1.f+expf(-x)); }

static __device__ __forceinline__ ushort_t f2bf(float f){
  unsigned u = __float_as_uint(f);
  u = u + 0x7fffu + ((u>>16)&1u);
  return (ushort_t)(u>>16);
}
static __device__ __forceinline__ float bflo(unsigned q){ return __uint_as_float(q << 16); }
static __device__ __forceinline__ float bfhi(unsigned q){ return __uint_as_float(q & 0xffff0000u); }

__device__ __forceinline__ void gload_lds16(const ushort_t* g, ushort_t* l){
  __builtin_amdgcn_global_load_lds((const __attribute__((address_space(1))) unsigned int*)(const void*)g,
                                   (__attribute__((address_space(3))) unsigned int*)(void*)l, 16, 0, 0);
}

// ---------------- fused gray+laplacian+window-variance flags ----------------
__global__ __launch_bounds__(256) void k_flags2(const float* __restrict__ rgb,
                                                float* __restrict__ flags){
  __shared__ float sg[70][71];
  int bx = blockIdx.x & 7, by = (blockIdx.x >> 3) & 7, b = blockIdx.x >> 6;
  int wy0 = by*16, wx0 = bx*16;
  int y0 = 4*wy0 - 1, x0 = 4*wx0 - 1;
  const float* p = rgb + (size_t)b*3*262144;
  int tid = threadIdx.x;
  for (int i = tid; i < 70*70; i += 256){
    int r = i/70, cX = i%70;
    int y = y0 + r, x = x0 + cX;
    float v = 0.f;
    if (y>=0 && y<512 && x>=0 && x<512){
      int ii = y*512+x;
      v = 0.299f*p[ii] + 0.587f*p[ii+262144] + 0.114f*p[ii+524288];
      v = fminf(fmaxf(v*255.f, 0.f), 255.f);
    }
    sg[r][cX] = v;
  }
  __syncthreads();
  int wy = wy0 + (tid>>4), wx = wx0 + (tid&15);
  if (wy > 126 || wx > 126) return;
  int ry = 4*(tid>>4) + 1, rx = 4*(tid&15) + 1;
  float s1 = 0.f, s2 = 0.f;
  #pragma unroll
  for (int iy=0; iy<8; ++iy){
    int r = ry+iy;
    #pragma unroll
    for (int ix=0; ix<8; ++ix){
      int cX = rx+ix;
      float c = sg[r][cX];
      float lap = sg[r-1][cX] + sg[r+1][cX] + sg[r][cX-1] + sg[r][cX+1] - 4.f*c;
      s1 += lap; s2 += lap*lap;
    }
  }
  float var = (s2 - s1*s1*(1.f/64.f)) * (1.f/63.f);
  flags[(size_t)b*16129 + wy*127 + wx] = (var < 50.f) ? 1.f : 0.f;
}

// ---------------- all three downsampled mask pairs in one launch ----------------
__global__ void k_masks3(const float* __restrict__ flags, const float* __restrict__ depth,
                         float* __restrict__ ri0, float* __restrict__ di0,
                         float* __restrict__ ri1, float* __restrict__ di1,
                         float* __restrict__ ri2, float* __restrict__ di2){
  int idx = blockIdx.x*256 + threadIdx.x;
  const int n0 = 8*4096, n1 = 8*1024, n2 = 8*256;
  float* ri; float* di; int h, st, i2;
  if (idx < n0){ ri=ri0; di=di0; h=64; st=8;  i2=idx; }
  else if (idx < n0+n1){ ri=ri1; di=di1; h=32; st=16; i2=idx-n0; }
  else if (idx < n0+n1+n2){ ri=ri2; di=di2; h=16; st=32; i2=idx-n0-n1; }
  else return;
  int b = i2/(h*h), i = i2%(h*h);
  int y = (i/h)*st, x = (i%h)*st;
  const float* f = flags + (size_t)b*16129;
  int fy = y>>2, fx = x>>2;
  float v = f[fy*127+fx];
  if (y>0)         v = fmaxf(v, f[(fy-1)*127+fx]);
  if (x>0)         v = fmaxf(v, f[fy*127+fx-1]);
  if (y>0 && x>0)  v = fmaxf(v, f[(fy-1)*127+fx-1]);
  ri[i2] = v;
  const int IHW = 262144;
  di[i2] = (depth[(size_t)b*3*IHW + 2*IHW + (size_t)y*512 + x] <= 0.f) ? 1.f : 0.f;
}

// ---------------- weights -> bf16, K-order (cb outer, kq inner): k' = (cb*9+kq)*64+cin ------
template<int C>
__global__ __launch_bounds__(256) void k_wrd2(const float* __restrict__ w, ushort_t* __restrict__ outp){
  __shared__ float swp[9*C];
  int co = blockIdx.x, tid = threadIdx.x;
  const int n = 9*C;
  const float* src = w + (size_t)co*n;
  for (int i=tid;i<n;i+=256) swp[i]=src[i];
  __syncthreads();
  ushort_t* dst = outp + (size_t)co*n;
  for (int j=tid;j<n;j+=256){
    int cb  = j / 576;
    int rem = j - cb*576;
    int kq  = rem >> 6;
    int cin = rem & 63;
    dst[j] = f2bf(swp[(cb*64 + cin)*9 + kq]);
  }
}

// ---------------- FUSED: feat -> padded NHWC bf16 + channel-row sums + per-position stats ----
template<int C, int H, int W>
__global__ __launch_bounds__(256) void k_prep(const float* __restrict__ rgbf,
                                              const float* __restrict__ depf,
                                              ushort_t* __restrict__ outp,
                                              float* __restrict__ gpart,
                                              float* __restrict__ pmean,
                                              float* __restrict__ pmax_){
  const int W2 = W+2, H2 = H+2, CB = C/64;
  const int NHSZ = B8*H2*W2*C;
  const int HW = H*W;
  __shared__ float st[64*66];
  __shared__ float red[4][64];
  int bi = blockIdx.x;
  int f  = bi & 1; bi >>= 1;          // 0=rgb feat, 1=dep feat
  int cb = bi % CB; bi /= CB;
  int yy = bi % H2;
  int b  = bi / H2;
  int tid = threadIdx.x;
  const float* in = (f==0) ? rgbf : depf;
  int ndir = f ^ 1;                    // nhwc dest dir
  ushort_t* outrow = outp + (size_t)ndir*NHSZ + ((size_t)(b*H2 + yy)*W2)*C + cb*64;
  bool pad_row = (yy == 0) || (yy == H2-1);
  if (!pad_row){
    int y = yy-1;
    const float* src = in + ((size_t)(b*C + cb*64)*H + y)*W;
    for (int i=tid; i<64*W; i+=256){
      int c = i / W, x = i % W;
      st[x*66 + c] = src[(size_t)c*H*W + x];
    }
  }
  __syncthreads();
  // (a) nhwc write
  for (int j=tid; j<W2*8; j+=256){
    int x = j >> 3, cc = (j & 7)*8;
    ushort_t tmp[8];
    if (pad_row || x == 0 || x == W2-1){
      #pragma unroll
      for (int q=0;q<8;++q) tmp[q]=0;
    } else {
      const float* sp = &st[(x-1)*66 + cc];
      float2 a0 = *(const float2*)(sp+0);
      float2 a1 = *(const float2*)(sp+2);
      float2 a2 = *(const float2*)(sp+4);
      float2 a3 = *(const float2*)(sp+6);
      tmp[0]=f2bf(a0.x); tmp[1]=f2bf(a0.y); tmp[2]=f2bf(a1.x); tmp[3]=f2bf(a1.y);
      tmp[4]=f2bf(a2.x); tmp[5]=f2bf(a2.y); tmp[6]=f2bf(a3.x); tmp[7]=f2bf(a3.y);
    }
    *(bf16x8*)&outrow[(size_t)x*C + cc] = *(bf16x8*)tmp;
  }
  if (pad_row) return;
  int y = yy - 1;
  // (b) per-channel row sums (4 threads/channel, LDS reduce)
  {
    int c = tid & 63, quarter = tid >> 6;
    float s = 0.f;
    for (int x = quarter; x < W; x += 4) s += st[x*66 + c];
    red[quarter][c] = s;
  }
  // (c) per-position sum/max over 64 channels (4-lane slices)
  if (tid < W*4){
    int x = tid >> 2, sl = tid & 3;
    float ps = 0.f, pmx = -INFINITY;
    #pragma unroll
    for (int k=0;k<16;++k){
      float v = st[x*66 + sl*16 + k];
      ps += v; pmx = fmaxf(pmx, v);
    }
    ps += __shfl_xor(ps, 1); pmx = fmaxf(pmx, __shfl_xor(pmx, 1));
    ps += __shfl_xor(ps, 2); pmx = fmaxf(pmx, __shfl_xor(pmx, 2));
    if (sl == 0){
      size_t po = ((size_t)f*CB + cb)*((size_t)B8*HW) + (size_t)b*HW + (size_t)y*W + x;
      pmean[po] = ps; pmax_[po] = pmx;
    }
  }
  __syncthreads();
  if (tid < 64){
    float t4 = red[0][tid]+red[1][tid]+red[2][tid]+red[3][tid];
    gpart[(((size_t)f*B8 + b)*H + y)*C + (size_t)cb*64 + tid] = t4;
  }
}

// ---------------- implicit-GEMM conv: 256x256 tile, 8 waves, pipelined 2-barrier schedule ----
template<int C, int H, int W, int KS>
__global__ __launch_bounds__(512)
void k_gemm_conv(const ushort_t* __restrict__ Aw, const ushort_t* __restrict__ nh,
                 ushort_t* __restrict__ Gm){
  const int K9 = 9*C;
  const int HW = H*W;
  const int N  = B8*HW;
  const int H2 = H+2, W2 = W+2;
  const int NT_N = N/256, NT_M = C/256;
  const int KCT = 36;
  const int NHSZ = B8*H2*W2*C;
  __shared__ ushort_t sA[2][16384];       // [slot][quad-major 256 rows][64]
  __shared__ ushort_t sB[2][16384];       // [slot][256 rows][64]
  int tid = threadIdx.x;

  const int nwg = 2*KS*NT_M*NT_N;         // = 256 for all scales
  const int MK  = 2*KS*NT_M;
  int bid = blockIdx.x;
  int swz = (bid & 7)*(nwg >> 3) + (bid >> 3);
  int mk  = swz % MK;
  int n_t = swz / MK;
  int m_t = mk % NT_M;
  int kz2 = mk / NT_M;
  int dir = kz2 / KS, kz = kz2 % KS;

  const ushort_t* nhd = nh + (size_t)dir*NHSZ;
  int m0 = m_t*256, n0 = n_t*256;
  int l = tid & 63, wv_id = tid >> 6;
  int wm = wv_id >> 2, wn = wv_id & 3;    // 2M x 4N waves
  int lrow = l & 15, lq = l >> 4;
  int lx7 = lrow & 7;

  long long aoffA[2][2], boffB[2][2];
  #pragma unroll
  for (int h=0; h<2; ++h){
    #pragma unroll
    for (int j=0; j<2; ++j){
      int c = j*512 + tid;
      int lr = h*128 + (c>>3);
      int slot = c & 7;
      int lslot = slot ^ (lr & 7);        // T2: pre-swizzled source
      int q_ = lr >> 6, wm_ = (lr>>5)&1, loc = lr & 31;
      int r = wm_*128 + q_*32 + loc;      // invert quad-major map
      aoffA[h][j] = (long long)(m0 + r)*K9 + lslot*8;
      int nn = n0 + lr;
      int b_ = nn / HW, rhw = nn % HW;
      int y = rhw / W, x = rhw % W;
      boffB[h][j] = ((long long)(b_*H2 + y + 1)*W2 + (x + 1))*(long long)C + lslot*8;
    }
  }

#define STAGE_A(s_, h_, kc_) do{                                    \
    long long oK = (long long)(kc_) << 6;                           \
    ushort_t* d0 = &sA[s_][(h_)*8192 + tid*8];                      \
    gload_lds16(Aw + aoffA[h_][0] + oK, d0);                        \
    gload_lds16(Aw + aoffA[h_][1] + oK, d0 + 4096);                 \
  }while(0)
#define STAGE_B(s_, h_, kc_) do{                                    \
    int cb_ = (kc_)/9, kq_ = (kc_) - cb_*9;                         \
    long long dv = (long long)((kq_/3 - 1)*W2 + (kq_%3 - 1))*C + ((long long)cb_<<6); \
    ushort_t* d0 = &sB[s_][(h_)*8192 + tid*8];                      \
    gload_lds16(nhd + boffB[h_][0] + dv, d0);                       \
    gload_lds16(nhd + boffB[h_][1] + dv, d0 + 4096);                \
  }while(0)

  f32x4 acc[8][4];
  #pragma unroll
  for (int i=0;i<8;++i)
    #pragma unroll
    for (int j=0;j<4;++j) acc[i][j] = (f32x4){0.f,0.f,0.f,0.f};

  int kc0 = kz*KCT;

  STAGE_A(0,0,kc0);   STAGE_A(0,1,kc0);
  STAGE_B(0,0,kc0);   STAGE_B(0,1,kc0);
  STAGE_B(1,0,kc0+1); STAGE_B(1,1,kc0+1);
  STAGE_A(1,0,kc0+1);
  asm volatile("s_waitcnt vmcnt(6)" ::: "memory");
  __builtin_amdgcn_s_barrier();

  for (int t=0; t<KCT; ++t){
    int cur = t & 1, nxt = cur ^ 1;
    int kc = kc0 + t;
    bf16x8 bf[4][2], afA[2][2], afB[2][2];

    // ---- P0 ----
    #pragma unroll
    for (int ni=0;ni<4;++ni)
      #pragma unroll
      for (int kk=0;kk<2;++kk)
        bf[ni][kk] = *(const bf16x8*)&sB[cur][(wn*64 + ni*16 + lrow)*64 + ((kk*4+lq)^lx7)*8];
    #pragma unroll
    for (int mi=0;mi<2;++mi)
      #pragma unroll
      for (int kk=0;kk<2;++kk)
        afA[mi][kk] = *(const bf16x8*)&sA[cur][(wm*32 + mi*16 + lrow)*64 + ((kk*4+lq)^lx7)*8];
    #pragma unroll
    for (int mi=0;mi<2;++mi)
      #pragma unroll
      for (int kk=0;kk<2;++kk)
        afB[mi][kk] = *(const bf16x8*)&sA[cur][(64 + wm*32 + mi*16 + lrow)*64 + ((kk*4+lq)^lx7)*8];
    if (t+1 < KCT) STAGE_A(nxt,1,kc+1);
    __builtin_amdgcn_s_setprio(1);
    #pragma unroll
    for (int kk=0;kk<2;++kk)
      #pragma unroll
      for (int mi=0;mi<2;++mi)
        #pragma unroll
        for (int ni=0;ni<4;++ni)
          acc[mi][ni] = __builtin_amdgcn_mfma_f32_16x16x32_bf16(afA[mi][kk], bf[ni][kk], acc[mi][ni], 0,0,0);
    __builtin_amdgcn_s_setprio(0);
    asm volatile("s_waitcnt lgkmcnt(0)" ::: "memory");
    __builtin_amdgcn_sched_barrier(0);
    __builtin_amdgcn_s_barrier();                       // BARRIER-1

    // ---- P1 ----
    #pragma unroll
    for (int mi=0;mi<2;++mi)
      #pragma unroll
      for (int kk=0;kk<2;++kk)
        afA[mi][kk] = *(const bf16x8*)&sA[cur][(128 + wm*32 + mi*16 + lrow)*64 + ((kk*4+lq)^lx7)*8];
    if (t+2 < KCT) STAGE_B(cur,0,kc+2);
    __builtin_amdgcn_s_setprio(1);
    #pragma unroll
    for (int kk=0;kk<2;++kk)
      #pragma unroll
      for (int mi=0;mi<2;++mi)
        #pragma unroll
        for (int ni=0;ni<4;++ni)
          acc[2+mi][ni] = __builtin_amdgcn_mfma_f32_16x16x32_bf16(afB[mi][kk], bf[ni][kk], acc[2+mi][ni], 0,0,0);
    __builtin_amdgcn_s_setprio(0);

    // ---- P2 ----
    #pragma unroll
    for (int mi=0;mi<2;++mi)
      #pragma unroll
      for (int kk=0;kk<2;++kk)
        afB[mi][kk] = *(const bf16x8*)&sA[cur][(192 + wm*32 + mi*16 + lrow)*64 + ((kk*4+lq)^lx7)*8];
    if (t+2 < KCT) STAGE_B(cur,1,kc+2);
    __builtin_amdgcn_s_setprio(1);
    #pragma unroll
    for (int kk=0;kk<2;++kk)
      #pragma unroll
      for (int mi=0;mi<2;++mi)
        #pragma unroll
        for (int ni=0;ni<4;++ni)
          acc[4+mi][ni] = __builtin_amdgcn_mfma_f32_16x16x32_bf16(afA[mi][kk], bf[ni][kk], acc[4+mi][ni], 0,0,0);
    __builtin_amdgcn_s_setprio(0);

    // ---- P3 ----
    if (t+2 < KCT) STAGE_A(cur,0,kc+2);
    __builtin_amdgcn_s_setprio(1);
    #pragma unroll
    for (int kk=0;kk<2;++kk)
      #pragma unroll
      for (int mi=0;mi<2;++mi)
        #pragma unroll
        for (int ni=0;ni<4;++ni)
          acc[6+mi][ni] = __builtin_amdgcn_mfma_f32_16x16x32_bf16(afB[mi][kk], bf[ni][kk], acc[6+mi][ni], 0,0,0);
    __builtin_amdgcn_s_setprio(0);
    if (t+2 < KCT) { asm volatile("s_waitcnt vmcnt(6)" ::: "memory"); }
    else           { asm volatile("s_waitcnt vmcnt(0)" ::: "memory"); }
    __builtin_amdgcn_sched_barrier(0);
    __builtin_amdgcn_s_barrier();                       // BARRIER-2
  }
#undef STAGE_A
#undef STAGE_B

  // ---- epilogue: C-write (bf16) ----
  ushort_t* po = Gm + (size_t)kz2*C*N;
  #pragma unroll
  for (int ai=0;ai<8;++ai)
    #pragma unroll
    for (int ni=0;ni<4;++ni)
      #pragma unroll
      for (int r=0;r<4;++r)
        po[(size_t)(m0 + wm*128 + ai*16 + lq*4 + r)*N + n0 + wn*64 + ni*16 + lrow] = f2bf(acc[ai][ni][r]);
}

// ---------------- FUSED attention tail: spatial attention (sp recompute in LDS) + MLP --------
template<int C, int H, int R>
__global__ __launch_bounds__(256) void k_att(const float* __restrict__ pmean,
                                             const float* __restrict__ pmax_,
                                             const float* __restrict__ gpart,
                                             const float* __restrict__ sa,
                                             const float* __restrict__ w1,
                                             const float* __restrict__ w2,
                                             float* __restrict__ sw,
                                             float* __restrict__ cw,
                                             int Rr, float invHW){
  const int CG = C/64;
  const int HW = H*H;
  const int swB = B8*(H/R);
  __shared__ float s_sa[196];
  __shared__ float spm[(R+6)*H];
  __shared__ float spx[(R+6)*H];
  __shared__ float sg[1024];
  __shared__ float sh[64];
  int dir = blockIdx.y;
  int bx = blockIdx.x;
  int tid = threadIdx.x;
  float invC = 1.f/(float)C;

  if (bx < swB){
    if (tid < 196) s_sa[tid] = sa[tid];
    int b = bx / (H/R), rb = bx % (H/R);
    int y0 = rb*R;
    for (int i = tid; i < (R+6)*H; i += 256){
      int y = y0 - 3 + i/H;
      int x = i % H;
      float s = 0.f, m = -INFINITY;
      if (y >= 0 && y < H){
        #pragma unroll
        for (int g=0; g<CG; ++g){
          size_t po = ((size_t)dir*CG + g)*((size_t)B8*HW) + (size_t)b*HW + (size_t)y*H + x;
          s += pmean[po];
          m = fmaxf(m, pmax_[po]);
        }
      }
      spm[i] = s*invC;
      spx[i] = m;
    }
    __syncthreads();
    int x = tid % H, yl = tid / H;
    int y = y0 + yl;
    float inv_w = 2.f/(float)(H-1);
    float acc = 0.f;
    for (int ky=0;ky<7;++ky){
      int gy = y+ky-3;
      if (gy<0 || gy>=H) continue;
      float ysv = -1.f + gy*inv_w;
      int lr = yl + ky;
      for (int kx=0;kx<7;++kx){
        int gx = x+kx-3;
        if (gx<0 || gx>=H) continue;
        float xsv = -1.f + gx*inv_w;
        int kk = ky*7+kx;
        acc += s_sa[kk]*spm[lr*H+gx] + s_sa[49+kk]*spx[lr*H+gx]
             + s_sa[98+kk]*xsv + s_sa[147+kk]*ysv;
      }
    }
    sw[(size_t)dir*B8*HW + (size_t)b*HW + (size_t)y*H + x] = sigmoidf_(acc);
  } else {
    int b = bx - swB;
    int Rch = C/16;
    const float* gp = gpart + (((size_t)dir*B8 + b)*H)*C;
    for (int c=tid;c<C;c+=256){
      float s = 0.f;
      for (int sp=0; sp<H; ++sp) s += gp[(size_t)sp*C + c];
      sg[c] = s*invHW;
    }
    __syncthreads();
    int r = tid>>2, q = tid&3;
    if (r < Rch){
      float s = 0.f;
      for (int c=q;c<C;c+=4) s += w1[(size_t)r*C + c]*sg[c];
      s += __shfl_xor(s,1); s += __shfl_xor(s,2);
      if (q==0) sh[r] = fmaxf(s, 0.f);
    }
    __syncthreads();
    for (int c2=tid; c2<C; c2+=256){
      float s = 0.f;
      for (int rr=0;rr<Rch;++rr) s += w2[(size_t)c2*Rch + rr]*sh[rr];
      cw[(size_t)dir*B8*C + (size_t)b*C + c2] = sigmoidf_(s);
    }
  }
}

// ---------------- fused BN stats + masked compose; G row cached in dynamic LDS --------------
__global__ __launch_bounds__(256)
void k_bnfinal(const float* __restrict__ rgbf, const float* __restrict__ depf,
               const ushort_t* __restrict__ G,
               const float* __restrict__ g, const float* __restrict__ bb,
               const float* __restrict__ swp, const float* __restrict__ cwp,
               const float* __restrict__ ri, const float* __restrict__ di,
               float* __restrict__ out_r, float* __restrict__ out_d,
               int C, int HW, int hwShift, int ks){
  extern __shared__ char bnf_smem[];
  int c = blockIdx.x, dir = blockIdx.y, tid = threadIdx.x;
  int N = B8*HW;
  size_t MN = (size_t)C*N;
  const ushort_t* p0 = G + (size_t)dir*ks*MN + (size_t)c*N;
  const float* main_ = (dir==0) ? rgbf : depf;
  const float* mask  = (dir==0) ? ri : di;
  float* out = (dir==0) ? out_r : out_d;

  float s1 = 0.f, s2 = 0.f;
  if (ks == 1){
    uint4* cache = (uint4*)bnf_smem;
    for (int i = tid*8; i < N; i += 2048){
      uint4 q = *(const uint4*)(p0 + i);
      cache[i>>3] = q;
      float v0=bflo(q.x), v1=bfhi(q.x), v2=bflo(q.y), v3=bfhi(q.y);
      float v4=bflo(q.z), v5=bfhi(q.z), v6=bflo(q.w), v7=bfhi(q.w);
      s1 += v0+v1+v2+v3+v4+v5+v6+v7;
      s2 += v0*v0+v1*v1+v2*v2+v3*v3+v4*v4+v5*v5+v6*v6+v7*v7;
    }
  } else {
    float* cache = (float*)bnf_smem;
    for (int i = tid*8; i < N; i += 2048){
      float v[8];
      #pragma unroll
      for (int q=0;q<8;++q) v[q]=0.f;
      for (int kz=0; kz<ks; ++kz){
        uint4 q = *(const uint4*)(p0 + (size_t)kz*MN + i);
        v[0]+=bflo(q.x); v[1]+=bfhi(q.x); v[2]+=bflo(q.y); v[3]+=bfhi(q.y);
        v[4]+=bflo(q.z); v[5]+=bfhi(q.z); v[6]+=bflo(q.w); v[7]+=bfhi(q.w);
      }
      #pragma unroll
      for (int q=0;q<8;++q){ cache[i+q] = v[q]; s1 += v[q]; s2 += v[q]*v[q]; }
    }
  }
  __shared__ float sb1[4], sb2[4];
  __shared__ float sab[2];
  #pragma unroll
  for (int off=32; off; off>>=1){ s1 += __shfl_down(s1,off); s2 += __shfl_down(s2,off); }
  int wid = tid>>6;
  if ((tid&63)==0){ sb1[wid]=s1; sb2[wid]=s2; }
  __syncthreads();
  if (tid==0){
    float t1 = sb1[0]+sb1[1]+sb1[2]+sb1[3];
    float t2 = sb2[0]+sb2[1]+sb2[2]+sb2[3];
    float Nf = (float)N;
    float mean = t1/Nf;
    float var  = t2/Nf - mean*mean;
    float a = g[c] / sqrtf(var + 1e-5f);
    sab[0] = a;
    sab[1] = bb[c] - mean*a;
  }
  __syncthreads();
  float a = sab[0], bta = sab[1];

  for (int i = tid*8; i < N; i += 2048){
    float v[8];
    if (ks == 1){
      uint4 q = ((const uint4*)bnf_smem)[i>>3];
      v[0]=bflo(q.x); v[1]=bfhi(q.x); v[2]=bflo(q.y); v[3]=bfhi(q.y);
      v[4]=bflo(q.z); v[5]=bfhi(q.z); v[6]=bflo(q.w); v[7]=bfhi(q.w);
    } else {
      #pragma unroll
      for (int q=0;q<8;++q) v[q] = ((const float*)bnf_smem)[i+q];
    }
    int b  = i >> hwShift;
    int hw = i - (b << hwShift);
    const float* mkp = mask + (size_t)b*HW + hw;
    const float* mnp = main_ + ((size_t)b*C + c)*HW + hw;
    const float* swq = swp + (size_t)dir*B8*HW + (size_t)b*HW + hw;
    float cwv = 2.f * cwp[(size_t)dir*B8*C + (size_t)b*C + c];
    float4 mk0 = *(const float4*)(mkp),   mk1 = *(const float4*)(mkp+4);
    float4 mn0 = *(const float4*)(mnp),   mn1 = *(const float4*)(mnp+4);
    float4 sw0 = *(const float4*)(swq),   sw1 = *(const float4*)(swq+4);
    float4 o0, o1;
    o0.x = (mk0.x > 0.5f) ? fmaxf(a*v[0] + bta, 0.f)*sw0.x*cwv : mn0.x;
    o0.y = (mk0.y > 0.5f) ? fmaxf(a*v[1] + bta, 0.f)*sw0.y*cwv : mn0.y;
    o0.z = (mk0.z > 0.5f) ? fmaxf(a*v[2] + bta, 0.f)*sw0.z*cwv : mn0.z;
    o0.w = (mk0.w > 0.5f) ? fmaxf(a*v[3] + bta, 0.f)*sw0.w*cwv : mn0.w;
    o1.x = (mk1.x > 0.5f) ? fmaxf(a*v[4] + bta, 0.f)*sw1.x*cwv : mn1.x;
    o1.y = (mk1.y > 0.5f) ? fmaxf(a*v[5] + bta, 0.f)*sw1.y*cwv : mn1.y;
    o1.z = (mk1.z > 0.5f) ? fmaxf(a*v[6] + bta, 0.f)*sw1.z*cwv : mn1.z;
    o1.w = (mk1.w > 0.5f) ? fmaxf(a*v[7] + bta, 0.f)*sw1.w*cwv : mn1.w;
    float* op = out + ((size_t)b*C + c)*HW + hw;
    *(float4*)(op)   = o0;
    *(float4*)(op+4) = o1;
  }
}

extern "C" void kernel_launch(void* const* d_in, const int* in_sizes, int n_in,
                              void* d_out, int out_size, void* d_ws, size_t ws_size,
                              hipStream_t stream){
  (void)in_sizes; (void)n_in; (void)out_size; (void)ws_size;
  const int B = B8;
  const float* rgb_feat[3] = {(const float*)d_in[0], (const float*)d_in[2], (const float*)d_in[4]};
  const float* dep_feat[3] = {(const float*)d_in[1], (const float*)d_in[3], (const float*)d_in[5]};
  const float* rgb_img = (const float*)d_in[6];
  const float* dep_img = (const float*)d_in[7];

  const int Cs[3]   = {256, 512, 1024};
  const int hs[3]   = {64, 32, 16};
  const int HWs[3]  = {64*64, 32*32, 16*16};
  const int KSs[3]  = {1, 2, 4};
  const int HWSH[3] = {12, 10, 8};
  const unsigned BNSM[3] = {65536, 32768, 8192};   // bnfinal dynamic LDS bytes

  float* ws = (float*)d_ws;
  ushort_t* Gm = (ushort_t*)ws;            // 16,777,216 bf16 (= 8,388,608 floats)
  float* flags = ws;                       // dead before gemm writes Gm
  float* rdbase = ws + 8388608;
  float* ri[3]; float* di[3];
  {
    size_t o = 0;
    for (int s=0;s<3;++s){
      ri[s] = rdbase + o; o += (size_t)B*hs[s]*hs[s];
      di[s] = rdbase + o; o += (size_t)B*hs[s]*hs[s];
    }
  }
  float* SB = rdbase + 86016;              // scratch base (nhbf | wbf)
  float* ST = SB + 9220096;                // stats (written by k_prep alongside nhbf)
  float* swb    = ST + 0;         // 65536
  float* gpart  = ST + 65536;     // 262144  [dir][b][H][C]
  float* cwb    = ST + 327680;    // 16384
  float* pmeanp = ST + 344064;    // 262144  [dir][CG][B*HW]
  float* pmaxp  = ST + 606208;    // 262144  -> ends 868,352

  // stage A: masks
  k_flags2<<<512, 256, 0, stream>>>(rgb_img, flags);
  k_masks3<<<168, 256, 0, stream>>>(flags, dep_img, ri[0], di[0], ri[1], di[1], ri[2], di[2]);

  const size_t outoff_r[3] = {0,         8388608u,  12582912u};
  const size_t outoff_d[3] = {14680064u, 23068672u, 27262976u};
  float* outp = (float*)d_out;

  for (int s=0;s<3;++s){
    const float* ftw = (const float*)d_in[8 +6*s];
    const float* bng = (const float*)d_in[9 +6*s];
    const float* bnb = (const float*)d_in[10+6*s];
    const float* saw = (const float*)d_in[11+6*s];
    const float* ca1 = (const float*)d_in[12+6*s];
    const float* ca2 = (const float*)d_in[13+6*s];
    int C = Cs[s], HW = HWs[s], h = hs[s];
    int BHW = B*HW;
    int ks = KSs[s];

    size_t nh_f = (size_t)B*(h+2)*(h+2)*C;           // shorts per dir; 2 dirs = nh_f floats
    ushort_t* nhbf = (ushort_t*)SB;
    ushort_t* wbf  = (ushort_t*)(SB + nh_f);

    if (s==0) k_wrd2<256> <<<256,  256, 0, stream>>>(ftw, wbf);
    if (s==1) k_wrd2<512> <<<512,  256, 0, stream>>>(ftw, wbf);
    if (s==2) k_wrd2<1024><<<1024, 256, 0, stream>>>(ftw, wbf);

    {
      unsigned nb = (unsigned)(B*(h+2)*(C/64)*2);
      if (s==0) k_prep<256, 64,64><<<nb, 256, 0, stream>>>(rgb_feat[s], dep_feat[s], nhbf, gpart, pmeanp, pmaxp);
      if (s==1) k_prep<512, 32,32><<<nb, 256, 0, stream>>>(rgb_feat[s], dep_feat[s], nhbf, gpart, pmeanp, pmaxp);
      if (s==2) k_prep<1024,16,16><<<nb, 256, 0, stream>>>(rgb_feat[s], dep_feat[s], nhbf, gpart, pmeanp, pmaxp);
    }

    if (s==0) k_gemm_conv<256, 64,64,1><<<256, 512, 0, stream>>>(wbf, nhbf, Gm);
    if (s==1) k_gemm_conv<512, 32,32,2><<<256, 512, 0, stream>>>(wbf, nhbf, Gm);
    if (s==2) k_gemm_conv<1024,16,16,4><<<256, 512, 0, stream>>>(wbf, nhbf, Gm);

    // fused attention tail (spatial attn + channel MLP in one launch)
    {
      float invHW = 1.f/(float)HW;
      if (s==0) k_att<256, 64, 4><<<dim3((unsigned)(B*16 + B),2), 256, 0, stream>>>(pmeanp, pmaxp, gpart, saw, ca1, ca2, swb, cwb, 0, invHW);
      if (s==1) k_att<512, 32, 8><<<dim3((unsigned)(B*4  + B),2), 256, 0, stream>>>(pmeanp, pmaxp, gpart, saw, ca1, ca2, swb, cwb, 0, invHW);
      if (s==2) k_att<1024,16,16><<<dim3((unsigned)(B*1  + B),2), 256, 0, stream>>>(pmeanp, pmaxp, gpart, saw, ca1, ca2, swb, cwb, 0, invHW);
    }

    k_bnfinal<<<dim3(C,2), 256, BNSM[s], stream>>>(
        rgb_feat[s], dep_feat[s], Gm, bng, bnb, swb, cwb,
        ri[s], di[s], outp + outoff_r[s], outp + outoff_d[s], C, HW, HWSH[s], ks);
  }
}